// Round 13
// baseline (236.792 us; speedup 1.0000x reference)
//
#include <hip/hip_runtime.h>
#include <hip/hip_bf16.h>
#include <stdint.h>

#define NROWS 8192
#define KDIM  512
#define NC    11014
#define PADC  11264      // 44 * 256
#define CT    44         // column tiles of 256
#define RTt   32         // row tiles of 256
#define NCHUNK (CT * 4)  // 176 chunks of 64 cols
#define NKT   8          // K tiles of 64

#define SS    30.0f
#define COSM  0.8253356149096783f
#define SINM  0.5646424733950354f
#define THv  (-0.8253356149096783f)
#define MMv   0.33878548403702126f

typedef __attribute__((ext_vector_type(4))) float  f32x4;
typedef __attribute__((ext_vector_type(8))) __bf16 bf16x8;

// async global->LDS, 16B per lane; LDS dest is wave-uniform base + lane*16.
__device__ __forceinline__ void async16(const void* g, void* l) {
  __builtin_amdgcn_global_load_lds(
      (const __attribute__((address_space(1))) unsigned int*)(uintptr_t)g,
      (__attribute__((address_space(3))) unsigned int*)(uint32_t)(uintptr_t)l,
      16, 0, 0);
}

// ---------------- kernel 0: L2-normalize rows of x,w -> bf16 (wave per row) --
__global__ void norm_kernel(const float* __restrict__ x, const float* __restrict__ w,
                            __hip_bfloat16* __restrict__ xn, __hip_bfloat16* __restrict__ wn) {
  const int wid  = blockIdx.x * 4 + (threadIdx.x >> 6);
  const int lane = threadIdx.x & 63;
  const bool isx = (wid < NROWS);
  const int r = isx ? wid : (wid - NROWS);
  const bool pad = (!isx) && (r >= NC);
  const float* p = isx ? (x + (size_t)r * KDIM) : (w + (size_t)r * KDIM);
  f32x4 a = {0.f, 0.f, 0.f, 0.f}, b = {0.f, 0.f, 0.f, 0.f};
  if (!pad) {
    a = ((const f32x4*)p)[2 * lane];
    b = ((const f32x4*)p)[2 * lane + 1];
  }
  float ss = a[0]*a[0] + a[1]*a[1] + a[2]*a[2] + a[3]*a[3]
           + b[0]*b[0] + b[1]*b[1] + b[2]*b[2] + b[3]*b[3];
#pragma unroll
  for (int d = 1; d < 64; d <<= 1) ss += __shfl_xor(ss, d);
  const float scale = pad ? 0.f : (1.0f / fmaxf(sqrtf(ss), 1e-12f));
  __hip_bfloat16* o = isx ? (xn + (size_t)r * KDIM) : (wn + (size_t)r * KDIM);
  bf16x8 ov;
#pragma unroll
  for (int e = 0; e < 4; ++e) ov[e]     = (__bf16)(a[e] * scale);
#pragma unroll
  for (int e = 0; e < 4; ++e) ov[e + 4] = (__bf16)(b[e] * scale);
  *(bf16x8*)(o + lane * 8) = ov;
}

// ---- phase helpers (template params keep acc indexing static — rule #20) ----
__device__ __forceinline__ bf16x8 ldsv(const char* p) { return *(const bf16x8*)p; }

template<int MH>
__device__ __forceinline__ void readA(const char* base, int aRowB, int x0, int x1,
                                      bf16x8 af[4][2]) {
#pragma unroll
  for (int mm = 0; mm < 4; ++mm) {
    af[mm][0] = ldsv(base + (MH * 4 + mm) * 2048 + aRowB + x0);
    af[mm][1] = ldsv(base + (MH * 4 + mm) * 2048 + aRowB + x1);
  }
}
template<int NH>
__device__ __forceinline__ void readB(const char* base, int bRowB, int x0, int x1,
                                      bf16x8 bq[2][2]) {
#pragma unroll
  for (int nn = 0; nn < 2; ++nn) {
    bq[nn][0] = ldsv(base + bRowB + (NH * 2 + nn) * 2048 + x0);
    bq[nn][1] = ldsv(base + bRowB + (NH * 2 + nn) * 2048 + x1);
  }
}
template<int MH, int NH>
__device__ __forceinline__ void mfma16(bf16x8 af[4][2], bf16x8 bq[2][2],
                                       f32x4 (&acc)[8][4]) {
#pragma unroll
  for (int mm = 0; mm < 4; ++mm)
#pragma unroll
    for (int nn = 0; nn < 2; ++nn) {
      acc[MH*4+mm][NH*2+nn] = __builtin_amdgcn_mfma_f32_16x16x32_bf16(
          af[mm][0], bq[nn][0], acc[MH*4+mm][NH*2+nn], 0, 0, 0);
      acc[MH*4+mm][NH*2+nn] = __builtin_amdgcn_mfma_f32_16x16x32_bf16(
          af[mm][1], bq[nn][1], acc[MH*4+mm][NH*2+nn], 0, 0, 0);
    }
}

#define LGKM_FENCE()  do { asm volatile("s_waitcnt lgkmcnt(0)" ::: "memory"); \
                           __builtin_amdgcn_sched_barrier(0); } while (0)

// ---------------- kernel 1: 256x256 BK=64 8-wave phase-split GEMM ------------
// LDS: 8 half-slots of 16KB: dbuf d at d*65536; within: A0=0,B0=16384,
// A1=32768,B1=49152; each half [128 rows][64 k] bf16 with ks-XOR swizzle:
// byte(r,ks) = r*128 + ((ks^(r&7))*16). Staging of tile kt+1 targets dbuf 1-d
// (never the buffer being read) -> race-free; rendezvous = per-wave vmcnt(0)
// at ph3 end + barrier.
__global__ __launch_bounds__(512, 1) void gemm_arc(
    const __hip_bfloat16* __restrict__ xn, const __hip_bfloat16* __restrict__ wn,
    const int* __restrict__ label, float* __restrict__ out,
    float2* __restrict__ parts) {
  __shared__ __align__(16) char sm[131072];
  __shared__ int slbl[256];

  const int tid  = threadIdx.x;
  const int w    = tid >> 6;          // 0..7
  const int lane = tid & 63;
  const int wrow = w >> 2;            // 0..1 (row 128-block)
  const int wcol = w & 3;             // 0..3 (col 64-block)

  // XCD-affine decode (1408 = 8 XCD * 4 tr * 44 ct)
  const int bid = blockIdx.x;
  const int xcd = bid & 7;
  const int kq  = bid >> 3;           // 0..175
  const int tr  = xcd * 4 + (kq & 3);
  const int tc  = kq >> 2;
  const int rowBase = tr * 256;
  const int colBase = tc * 256;

  if (tid < 256) slbl[tid] = label[rowBase + tid];

  f32x4 acc[8][4];
#pragma unroll
  for (int m = 0; m < 8; ++m)
#pragma unroll
    for (int n = 0; n < 4; ++n)
      acc[m][n] = (f32x4){0.f, 0.f, 0.f, 0.f};

  // staging source (XOR-swizzled): thread -> row chunk c = i*8+w, row-in-chunk
  // lane>>3, k-slot (lane&7)^(lane>>3); 8-lane groups stay 128B-contiguous.
  const int sr3 = lane >> 3;
  const int sk  = (lane & 7) ^ sr3;
  const __hip_bfloat16* ga = xn + (size_t)(rowBase + w * 8 + sr3) * KDIM + sk * 8;
  const __hip_bfloat16* gb = wn + (size_t)(colBase + w * 8 + sr3) * KDIM + sk * 8;
  char* ldst = sm + w * 1024 + lane * 16;   // + dbuf*65536 + which*16384 + i*8192

  // read-side constants
  const int aSlot = wrow * 32768;                 // A0 or A1 slot
  const int bSlot = 16384 + (wcol >> 1) * 32768;  // B0 or B1 slot
  const int aRowB = (lane & 15) * 128;
  const int bRowB = (wcol & 1) * 8192 + (lane & 15) * 128;
  const int x0 = (((lane >> 4)    ) ^ (lane & 7)) * 16;
  const int x1 = (((lane >> 4) + 4) ^ (lane & 7)) * 16;

  // prologue: stage tile 0 into dbuf0 (8 loads), drain, sync
  async16(ga,              ldst);
  async16(ga +  64 * KDIM, ldst + 8192);
  async16(gb,              ldst + 16384);
  async16(gb +  64 * KDIM, ldst + 24576);
  async16(ga + 128 * KDIM, ldst + 32768);
  async16(ga + 192 * KDIM, ldst + 40960);
  async16(gb + 128 * KDIM, ldst + 49152);
  async16(gb + 192 * KDIM, ldst + 57344);
  asm volatile("s_waitcnt vmcnt(0)" ::: "memory");
  __builtin_amdgcn_s_barrier();

  bf16x8 af[4][2], bq[2][2];
  for (int kt = 0; kt < NKT; ++kt) {
    const char* dB = sm + (kt & 1) * 65536;
    char* sB = ldst + ((kt & 1) ^ 1) * 65536;
    const int kel = (kt + 1) * 64;
    const bool st = (kt + 1 < NKT);

    // ---- ph0: quadrant (0,0); stage A0,B0 of kt+1 ----
    readA<0>(dB + aSlot, aRowB, x0, x1, af);
    readB<0>(dB + bSlot, bRowB, x0, x1, bq);
    if (st) {
      async16(ga + kel,             sB);
      async16(ga + 64 * KDIM + kel, sB + 8192);
      async16(gb + kel,             sB + 16384);
      async16(gb + 64 * KDIM + kel, sB + 24576);
    }
    LGKM_FENCE();
    __builtin_amdgcn_s_setprio(1);
    mfma16<0, 0>(af, bq, acc);
    __builtin_amdgcn_s_setprio(0);
    __builtin_amdgcn_s_barrier();

    // ---- ph1: quadrant (0,1); stage A1,B1 of kt+1 ----
    readB<1>(dB + bSlot, bRowB, x0, x1, bq);
    if (st) {
      async16(ga + 128 * KDIM + kel, sB + 32768);
      async16(ga + 192 * KDIM + kel, sB + 40960);
      async16(gb + 128 * KDIM + kel, sB + 49152);
      async16(gb + 192 * KDIM + kel, sB + 57344);
    }
    LGKM_FENCE();
    __builtin_amdgcn_s_setprio(1);
    mfma16<0, 1>(af, bq, acc);
    __builtin_amdgcn_s_setprio(0);
    __builtin_amdgcn_s_barrier();

    // ---- ph2: quadrant (1,1) ----
    readA<1>(dB + aSlot, aRowB, x0, x1, af);
    LGKM_FENCE();
    __builtin_amdgcn_s_setprio(1);
    mfma16<1, 1>(af, bq, acc);
    __builtin_amdgcn_s_setprio(0);
    __builtin_amdgcn_s_barrier();

    // ---- ph3: quadrant (1,0); rendezvous ----
    readB<0>(dB + bSlot, bRowB, x0, x1, bq);
    LGKM_FENCE();
    __builtin_amdgcn_s_setprio(1);
    mfma16<1, 0>(af, bq, acc);
    __builtin_amdgcn_s_setprio(0);
    asm volatile("s_waitcnt vmcnt(0)" ::: "memory");  // my kt+1 staging landed
    __builtin_amdgcn_s_barrier();                     // everyone's landed
  }

  // ---- epilogue: margin + partials + direct stores ----
  const int g4 = lane >> 4;
  const int c4 = lane & 15;
#pragma unroll
  for (int m = 0; m < 8; ++m) {
#pragma unroll
    for (int j = 0; j < 4; ++j) {
      const int lrow = wrow * 128 + m * 16 + g4 * 4 + j;
      const int grow = rowBase + lrow;
      const int rl   = slbl[lrow];
      float v[4];
      float mx = -1e30f;
#pragma unroll
      for (int n = 0; n < 4; ++n) {
        const int gc = colBase + wcol * 64 + n * 16 + c4;
        float c = acc[m][n][j];
        float logit = c * SS;
        if (gc == rl) {  // rare; execz-skipped
          float sine = sqrtf(fmaxf(0.f, 1.f - c * c));
          float phi  = c * COSM - sine * SINM;
          phi = (c > THv) ? phi : (c - MMv);
          logit = phi * SS;
        }
        if (gc < NC) {
          out[(size_t)grow * NC + gc] = logit;
          v[n] = logit;
        } else {
          v[n] = -1e30f;
        }
        mx = fmaxf(mx, v[n]);
      }
#pragma unroll
      for (int d = 1; d < 16; d <<= 1) mx = fmaxf(mx, __shfl_xor(mx, d));
      float s = 0.f;
#pragma unroll
      for (int n = 0; n < 4; ++n)
        if (v[n] > -1e29f) s += __expf(v[n] - mx);
#pragma unroll
      for (int d = 1; d < 16; d <<= 1) s += __shfl_xor(s, d);
      if (c4 == 0) {
        parts[(size_t)(tc * 4 + wcol) * NROWS + grow] = make_float2(mx, s);
      }
    }
  }
}

// ---------------- kernel 2: per-row logsumexp merge + NLL --------------------
// 256 blocks x 256 threads; 8 lanes per row (part = lane>>3), shuffle combine.
__global__ void merge_loss(const float2* __restrict__ parts, const float* __restrict__ out,
                           const int* __restrict__ label, float* __restrict__ rowloss) {
  const int tid  = threadIdx.x;
  const int lane = tid & 63;
  const int wv   = tid >> 6;
  const int part = lane >> 3;
  const int row  = blockIdx.x * 32 + wv * 8 + (lane & 7);
  float M = -1e30f;
  for (int c = part; c < NCHUNK; c += 8)
    M = fmaxf(M, parts[(size_t)c * NROWS + row].x);
  M = fmaxf(M, __shfl_xor(M, 8));
  M = fmaxf(M, __shfl_xor(M, 16));
  M = fmaxf(M, __shfl_xor(M, 32));
  float Ssum = 0.f;
  for (int c = part; c < NCHUNK; c += 8) {
    float2 pp = parts[(size_t)c * NROWS + row];
    if (pp.x > -1e29f) Ssum += pp.y * __expf(pp.x - M);
  }
  Ssum += __shfl_xor(Ssum, 8);
  Ssum += __shfl_xor(Ssum, 16);
  Ssum += __shfl_xor(Ssum, 32);
  if (part == 0) {
    const float lt = out[(size_t)row * NC + label[row]];
    rowloss[row] = M + logf(Ssum) - lt;
  }
}

// ---------------- kernel 3: deterministic mean ------------------------------
__global__ void final_loss(const float* __restrict__ rowloss, float* __restrict__ out_loss) {
  double s = 0.0;
  for (int i = threadIdx.x; i < NROWS; i += 256) s += (double)rowloss[i];
  __shared__ double sd[256];
  sd[threadIdx.x] = s;
  __syncthreads();
  for (int step = 128; step > 0; step >>= 1) {
    if (threadIdx.x < step) sd[threadIdx.x] += sd[threadIdx.x + step];
    __syncthreads();
  }
  if (threadIdx.x == 0) out_loss[0] = (float)(sd[0] / (double)NROWS);
}

extern "C" void kernel_launch(void* const* d_in, const int* in_sizes, int n_in,
                              void* d_out, int out_size, void* d_ws, size_t ws_size,
                              hipStream_t stream) {
  const float* x     = (const float*)d_in[0];
  const int*   label = (const int*)d_in[1];
  const float* w     = (const float*)d_in[2];
  float* out = (float*)d_out;

  char* ws = (char*)d_ws;
  __hip_bfloat16* xn = (__hip_bfloat16*)ws;                      //  8,388,608 B
  __hip_bfloat16* wn = (__hip_bfloat16*)(ws + 8388608);          // 11,534,336 B
  float2* parts      = (float2*)(ws + 19922944);                 // 11,534,336 B
  float*  rowloss    = (float*)(ws + 31457280);                  //     32,768 B

  norm_kernel<<<dim3((NROWS + PADC) / 4), dim3(256), 0, stream>>>(x, w, xn, wn);
  gemm_arc<<<dim3(RTt * CT), dim3(512), 0, stream>>>(xn, wn, label, out, parts);
  merge_loss<<<dim3(256), dim3(256), 0, stream>>>(parts, out, label, rowloss);
  final_loss<<<dim3(1), dim3(256), 0, stream>>>(rowloss, out + (size_t)NROWS * NC);
}